// Round 5
// baseline (2513.283 us; speedup 1.0000x reference)
//
#include <hip/hip_runtime.h>

#define BATCHN 128
#define SEQT   2048
#define FEAT   64
#define UNITS  64
#define NCOL   256   // 4*UNITS gate columns
#define OUTD   6

typedef float v2f __attribute__((ext_vector_type(2)));

__device__ __forceinline__ float fast_exp2(float x) {
#if __has_builtin(__builtin_amdgcn_exp2f)
    return __builtin_amdgcn_exp2f(x);
#else
    return exp2f(x);
#endif
}
__device__ __forceinline__ float fast_rcp(float x) {
#if __has_builtin(__builtin_amdgcn_rcpf)
    return __builtin_amdgcn_rcpf(x);
#else
    return 1.0f / x;
#endif
}
__device__ __forceinline__ float sig_(float x) {
    return fast_rcp(1.0f + fast_exp2(-1.4426950408889634f * x));
}
__device__ __forceinline__ float tanh_(float x) {
    float xc = fminf(fmaxf(x, -15.0f), 15.0f);
    float e  = fast_exp2(2.8853900817779268f * xc);  // e^(2x)
    return (e - 1.0f) * fast_rcp(e + 1.0f);
}

// packed fp32 FMA (one VOP3P instr, 2 MACs)
__device__ __forceinline__ v2f pk_fma(v2f a, v2f b, v2f c) {
    v2f d;
    asm("v_pk_fma_f32 %0, %1, %2, %3" : "=v"(d) : "v"(a), "v"(b), "v"(c));
    return d;
}

// DPP cross-lane (VALU pipe)
template<int CTRL>
__device__ __forceinline__ float dppf(float v) {
    return __builtin_bit_cast(float, __builtin_amdgcn_update_dpp(
        0, __builtin_bit_cast(int, v), CTRL, 0xF, 0xF, true));
}
// reduce across the 4-lane k-split quad (lanes differ in bits [1:0])
__device__ __forceinline__ float red4(float v) {
    v += dppf<0xB1>(v);    // quad_perm [1,0,3,2] : xor 1
    v += dppf<0x4E>(v);    // quad_perm [2,3,0,1] : xor 2
    return v;
}

// raw workgroup barrier: drain LDS ops only, leave global loads in flight
__device__ __forceinline__ void bar_lds() {
    asm volatile("s_waitcnt lgkmcnt(0)\n\ts_barrier" ::: "memory");
}

__global__ __launch_bounds__(768, 1)
void lstm3_pipe2(const float* __restrict__ x,
                 const float* __restrict__ W0, const float* __restrict__ U0,
                 const float* __restrict__ b0,
                 const float* __restrict__ W1, const float* __restrict__ U1,
                 const float* __restrict__ b1,
                 const float* __restrict__ Wf, const float* __restrict__ bfv,
                 const float* __restrict__ Wo, const float* __restrict__ bov,
                 float* __restrict__ out)
{
    const int b   = blockIdx.x;
    const int tid = threadIdx.x;   // 0..767
    const int grp = tid >> 8;      // pipeline stage 0,1,2 (layer)
    const int lt  = tid & 255;     // 0..255 within group
    const int u   = lt >> 2;       // unit 0..63
    const int q   = lt & 3;        // k-split 0..3 (k-chunk of 16)

    __shared__ __align__(16) float lx[2][FEAT];        // x staging, by parity
    __shared__ __align__(16) float lh[3][2][UNITS];    // h per layer, by parity
    __shared__ float lact[UNITS];

    // ---- weights in registers: G0 <- W0/U0 ; G1,G2 <- W1/U1 (128 VGPRs) ----
    const float* Wsel = (grp == 0) ? W0 : W1;
    const float* Usel = (grp == 0) ? U0 : U1;
    const float* bsel = (grp == 0) ? b0 : b1;

    v2f wa[4][8], wb[4][8];
    float bias[4];
#pragma unroll
    for (int g = 0; g < 4; ++g) {
        const int col = (g << 6) + u;
#pragma unroll
        for (int j = 0; j < 8; ++j) {
            const int r = q * 16 + 2 * j;
            wa[g][j] = (v2f){Wsel[r * NCOL + col], Wsel[(r + 1) * NCOL + col]};
            wb[g][j] = (v2f){Usel[r * NCOL + col], Usel[(r + 1) * NCOL + col]};
        }
        bias[g] = bsel[col];
    }

    const float* xbase = x + (size_t)b * SEQT * FEAT;
    const bool xload = (grp == 0) && (lt < 16);

    // prologue: lx[1] <- x(0); in-flight regs xrA = x(1), xrB = x(2)
    float4 xrA = {0,0,0,0}, xrB = {0,0,0,0};
    if (xload) {
        float4 x0 = *(const float4*)(xbase + lt * 4);
        xrA = *(const float4*)(xbase + (size_t)1 * FEAT + lt * 4);
        xrB = *(const float4*)(xbase + (size_t)2 * FEAT + lt * 4);
        *(float4*)&lx[1][lt * 4] = x0;
    }
    if (tid < 3 * 2 * UNITS) ((float*)lh)[tid] = 0.f;
    __syncthreads();   // one-time full drain, fine

    // parity-indexed LDS pointers (in: G0<-lx, G1<-h0, G2<-h1)
    const float* inP0 = (grp == 0) ? &lx[0][q * 16] : &lh[grp - 1][0][q * 16];
    const float* inP1 = (grp == 0) ? &lx[1][q * 16] : &lh[grp - 1][1][q * 16];
    const float* rcP0 = &lh[grp][0][q * 16];
    const float* rcP1 = &lh[grp][1][q * 16];

    float c = 0.f;

    auto tick = [&](int tk, float4& cur, float4& /*nxt*/) {
        const int p = tk & 1;

        // publish x(tk+1) (loaded 2 ticks ago -> vmcnt wait is free),
        // then issue x(tk+3) into the freed register
        if (xload) {
            *(float4*)&lx[p][lt * 4] = cur;
            int tn = tk + 3; if (tn > SEQT - 1) tn = SEQT - 1;
            cur = *(const float4*)(xbase + (size_t)tn * FEAT + lt * 4);
        }

        const int t = tk - grp;
        if (t >= 0 && t < SEQT) {
            const float* inP = p ? inP0 : inP1;
            const float* rcP = p ? rcP0 : rcP1;

            v2f acc[4];
#pragma unroll
            for (int g = 0; g < 4; ++g) acc[g] = (v2f){0.f, 0.f};

#pragma unroll
            for (int kc = 0; kc < 4; ++kc) {           // feed-forward input
                float4 iv = *(const float4*)(inP + kc * 4);
                v2f i0 = (v2f){iv.x, iv.y}, i1 = (v2f){iv.z, iv.w};
#pragma unroll
                for (int g = 0; g < 4; ++g) {
                    acc[g] = pk_fma(i0, wa[g][2 * kc],     acc[g]);
                    acc[g] = pk_fma(i1, wa[g][2 * kc + 1], acc[g]);
                }
            }
#pragma unroll
            for (int kc = 0; kc < 4; ++kc) {           // recurrent h
                float4 rv = *(const float4*)(rcP + kc * 4);
                v2f r0 = (v2f){rv.x, rv.y}, r1 = (v2f){rv.z, rv.w};
#pragma unroll
                for (int g = 0; g < 4; ++g) {
                    acc[g] = pk_fma(r0, wb[g][2 * kc],     acc[g]);
                    acc[g] = pk_fma(r1, wb[g][2 * kc + 1], acc[g]);
                }
            }

            float z[4];
#pragma unroll
            for (int g = 0; g < 4; ++g)
                z[g] = red4(acc[g].x + acc[g].y) + bias[g];

            float ig = sig_(z[0]), fg = sig_(z[1]);
            float gg = tanh_(z[2]), og = sig_(z[3]);
            c = fg * c + ig * gg;
            float hn = og * tanh_(c);
            if (q == 0) lh[grp][p][u] = hn;
        }

        bar_lds();   // LDS-only drain; x loads stay in flight
    };

    for (int tk = 0; tk < SEQT + 2; tk += 2) {
        tick(tk,     xrA, xrB);
        tick(tk + 1, xrB, xrA);
    }

    // ---- dense head on final h2: written at tick SEQT+1 (parity 1) ----
    const float* h2f = lh[2][1];
    if (tid < UNITS) {
        float acc = bfv[tid];
#pragma unroll
        for (int k = 0; k < UNITS; ++k) acc += h2f[k] * Wf[k * 64 + tid];
        lact[tid] = fmaxf(acc, 0.f);
    }
    __syncthreads();
    if (tid < OUTD) {
        float acc = bov[tid];
#pragma unroll
        for (int k = 0; k < UNITS; ++k) acc += lact[k] * Wo[k * OUTD + tid];
        out[b * OUTD + tid] = acc;
    }
}

extern "C" void kernel_launch(void* const* d_in, const int* in_sizes, int n_in,
                              void* d_out, int out_size, void* d_ws, size_t ws_size,
                              hipStream_t stream) {
    const float* x   = (const float*)d_in[0];
    const float* W0  = (const float*)d_in[1];
    const float* U0  = (const float*)d_in[2];
    const float* b0  = (const float*)d_in[3];
    const float* W1  = (const float*)d_in[4];
    const float* U1  = (const float*)d_in[5];
    const float* b1  = (const float*)d_in[6];
    const float* Wf  = (const float*)d_in[7];
    const float* bfv = (const float*)d_in[8];
    const float* Wo  = (const float*)d_in[9];
    const float* bov = (const float*)d_in[10];
    float* out = (float*)d_out;

    lstm3_pipe2<<<BATCHN, 768, 0, stream>>>(x, W0, U0, b0, W1, U1, b1,
                                            Wf, bfv, Wo, bov, out);
}

// Round 6
// 2053.454 us; speedup vs baseline: 1.2239x; 1.2239x over previous
//
#include <hip/hip_runtime.h>

#define BATCHN 128
#define SEQT   2048
#define FEAT   64
#define UNITS  64
#define NCOL   256   // 4*UNITS gate columns
#define OUTD   6

typedef float v2f __attribute__((ext_vector_type(2)));

__device__ __forceinline__ float fast_exp2(float x) {
#if __has_builtin(__builtin_amdgcn_exp2f)
    return __builtin_amdgcn_exp2f(x);
#else
    return exp2f(x);
#endif
}
__device__ __forceinline__ float fast_rcp(float x) {
#if __has_builtin(__builtin_amdgcn_rcpf)
    return __builtin_amdgcn_rcpf(x);
#else
    return 1.0f / x;
#endif
}
__device__ __forceinline__ float sig_(float x) {
    return fast_rcp(1.0f + fast_exp2(-1.4426950408889634f * x));
}
__device__ __forceinline__ float tanh_(float x) {
    float xc = fminf(fmaxf(x, -15.0f), 15.0f);
    float e  = fast_exp2(2.8853900817779268f * xc);  // e^(2x)
    return (e - 1.0f) * fast_rcp(e + 1.0f);
}

// packed fp32 FMA via elementwise builtin -> v_pk_fma_f32, but with FREE
// register allocation (no inline-asm "v" constraints forcing accvgpr_read)
__device__ __forceinline__ v2f pk_fma(v2f a, v2f b, v2f c) {
    return __builtin_elementwise_fma(a, b, c);
}

// DPP cross-lane (VALU pipe)
template<int CTRL>
__device__ __forceinline__ float dppf(float v) {
    return __builtin_bit_cast(float, __builtin_amdgcn_update_dpp(
        0, __builtin_bit_cast(int, v), CTRL, 0xF, 0xF, true));
}
// reduce across the 4-lane k-split quad (lanes differ in bits [1:0])
__device__ __forceinline__ float red4(float v) {
    v += dppf<0xB1>(v);    // quad_perm [1,0,3,2] : xor 1
    v += dppf<0x4E>(v);    // quad_perm [2,3,0,1] : xor 2
    return v;
}

__global__ __launch_bounds__(768, 3)
void lstm3_pipe3(const float* __restrict__ x,
                 const float* __restrict__ W0, const float* __restrict__ U0,
                 const float* __restrict__ b0,
                 const float* __restrict__ W1, const float* __restrict__ U1,
                 const float* __restrict__ b1,
                 const float* __restrict__ Wf, const float* __restrict__ bfv,
                 const float* __restrict__ Wo, const float* __restrict__ bov,
                 float* __restrict__ out)
{
    const int b   = blockIdx.x;
    const int tid = threadIdx.x;   // 0..767
    const int grp = tid >> 8;      // pipeline stage 0,1,2 (layer)
    const int lt  = tid & 255;     // 0..255 within group
    const int u   = lt >> 2;       // unit 0..63
    const int q   = lt & 3;        // k-split 0..3 (k-chunk of 16)

    __shared__ __align__(16) float lx[2][FEAT];        // x(t) staging, by parity
    __shared__ __align__(16) float lh[3][2][UNITS];    // h per layer, by parity
    __shared__ float lact[UNITS];

    // ---- weights in registers: G0 <- W0/U0 ; G1,G2 <- W1/U1 (128 regs) ----
    const float* Wsel = (grp == 0) ? W0 : W1;
    const float* Usel = (grp == 0) ? U0 : U1;
    const float* bsel = (grp == 0) ? b0 : b1;

    v2f wa[4][8], wb[4][8];
    float bias[4];
#pragma unroll
    for (int g = 0; g < 4; ++g) {
        const int col = (g << 6) + u;
#pragma unroll
        for (int j = 0; j < 8; ++j) {
            const int r = q * 16 + 2 * j;
            wa[g][j] = (v2f){Wsel[r * NCOL + col], Wsel[(r + 1) * NCOL + col]};
            wb[g][j] = (v2f){Usel[r * NCOL + col], Usel[(r + 1) * NCOL + col]};
        }
        bias[g] = bsel[col];
    }

    // zero h state (both parities), preload x(0) into lx[1]
    if (tid < 3 * 2 * UNITS) ((float*)lh)[tid] = 0.f;
    const float* xbase = x + (size_t)b * SEQT * FEAT;
    const bool xload = (grp == 0) && (lt < 16);
    if (xload)
        *(float4*)&lx[1][lt * 4] = *(const float4*)(xbase + lt * 4);
    __syncthreads();

    // parity-indexed LDS source pointers (in: G0<-lx, G1<-h0, G2<-h1)
    const float* inP0 = (grp == 0) ? &lx[0][q * 16] : &lh[grp - 1][0][q * 16];
    const float* inP1 = (grp == 0) ? &lx[1][q * 16] : &lh[grp - 1][1][q * 16];
    const float* rcP0 = &lh[grp][0][q * 16];
    const float* rcP1 = &lh[grp][1][q * 16];

    float c = 0.f;

    for (int tk = 0; tk < SEQT + 2; ++tk) {
        const int p = tk & 1;          // write parity; reads use p^1
        const int t = tk - grp;        // this group's timestep
        const bool active = (t >= 0) && (t < SEQT);

        // loader lanes: issue global load of x(tk+1) at tick start
        // (lands during compute; the barrier drain at tick end is ~free)
        float4 xg;
        const bool loading = xload && (tk + 1 < SEQT);
        if (loading)
            xg = *(const float4*)(xbase + (size_t)(tk + 1) * FEAT + lt * 4);

        if (active) {
            const float* inP = p ? inP0 : inP1;
            const float* rcP = p ? rcP0 : rcP1;

            v2f acc[4];
#pragma unroll
            for (int g = 0; g < 4; ++g) acc[g] = (v2f){0.f, 0.f};

#pragma unroll
            for (int kc = 0; kc < 4; ++kc) {           // feed-forward input
                float4 iv = *(const float4*)(inP + kc * 4);
                v2f i0 = (v2f){iv.x, iv.y}, i1 = (v2f){iv.z, iv.w};
#pragma unroll
                for (int g = 0; g < 4; ++g) {
                    acc[g] = pk_fma(i0, wa[g][2 * kc],     acc[g]);
                    acc[g] = pk_fma(i1, wa[g][2 * kc + 1], acc[g]);
                }
            }
#pragma unroll
            for (int kc = 0; kc < 4; ++kc) {           // recurrent h
                float4 rv = *(const float4*)(rcP + kc * 4);
                v2f r0 = (v2f){rv.x, rv.y}, r1 = (v2f){rv.z, rv.w};
#pragma unroll
                for (int g = 0; g < 4; ++g) {
                    acc[g] = pk_fma(r0, wb[g][2 * kc],     acc[g]);
                    acc[g] = pk_fma(r1, wb[g][2 * kc + 1], acc[g]);
                }
            }

            float z[4];
#pragma unroll
            for (int g = 0; g < 4; ++g)
                z[g] = red4(acc[g].x + acc[g].y) + bias[g];

            float ig = sig_(z[0]), fg = sig_(z[1]);
            float gg = tanh_(z[2]), og = sig_(z[3]);
            c = fg * c + ig * gg;
            float hn = og * tanh_(c);
            if (q == 0) lh[grp][p][u] = hn;
        }

        // publish x(tk+1) for next tick's G0 read (writes parity p, reads p^1)
        if (loading)
            *(float4*)&lx[p][lt * 4] = xg;

        __syncthreads();
    }

    // ---- dense head on final h2: written at tick SEQT+1 (parity 1) ----
    const float* h2f = lh[2][1];
    if (tid < UNITS) {
        float acc = bfv[tid];
#pragma unroll
        for (int k = 0; k < UNITS; ++k) acc += h2f[k] * Wf[k * 64 + tid];
        lact[tid] = fmaxf(acc, 0.f);
    }
    __syncthreads();
    if (tid < OUTD) {
        float acc = bov[tid];
#pragma unroll
        for (int k = 0; k < UNITS; ++k) acc += lact[k] * Wo[k * OUTD + tid];
        out[b * OUTD + tid] = acc;
    }
}

extern "C" void kernel_launch(void* const* d_in, const int* in_sizes, int n_in,
                              void* d_out, int out_size, void* d_ws, size_t ws_size,
                              hipStream_t stream) {
    const float* x   = (const float*)d_in[0];
    const float* W0  = (const float*)d_in[1];
    const float* U0  = (const float*)d_in[2];
    const float* b0  = (const float*)d_in[3];
    const float* W1  = (const float*)d_in[4];
    const float* U1  = (const float*)d_in[5];
    const float* b1  = (const float*)d_in[6];
    const float* Wf  = (const float*)d_in[7];
    const float* bfv = (const float*)d_in[8];
    const float* Wo  = (const float*)d_in[9];
    const float* bov = (const float*)d_in[10];
    float* out = (float*)d_out;

    lstm3_pipe3<<<BATCHN, 768, 0, stream>>>(x, W0, U0, b0, W1, U1, b1,
                                            Wf, bfv, Wo, bov, out);
}

// Round 7
// 2005.969 us; speedup vs baseline: 1.2529x; 1.0237x over previous
//
#include <hip/hip_runtime.h>

#define BATCHN 128
#define SEQT   2048
#define FEAT   64
#define UNITS  64
#define NCOL   256   // 4*UNITS gate columns
#define OUTD   6
#define CH     20    // chunk stride in floats (16 data + 4 pad)
#define BUF    96    // operand buffer stride (4*CH=80, padded to 96 for 128B align)

typedef float v2f __attribute__((ext_vector_type(2)));

__device__ __forceinline__ float fast_exp2(float x) {
#if __has_builtin(__builtin_amdgcn_exp2f)
    return __builtin_amdgcn_exp2f(x);
#else
    return exp2f(x);
#endif
}
__device__ __forceinline__ float fast_rcp(float x) {
#if __has_builtin(__builtin_amdgcn_rcpf)
    return __builtin_amdgcn_rcpf(x);
#else
    return 1.0f / x;
#endif
}
__device__ __forceinline__ float sig_(float x) {
    return fast_rcp(1.0f + fast_exp2(-1.4426950408889634f * x));
}
__device__ __forceinline__ float tanh_(float x) {
    float xc = fminf(fmaxf(x, -15.0f), 15.0f);
    float e  = fast_exp2(2.8853900817779268f * xc);  // e^(2x)
    return (e - 1.0f) * fast_rcp(e + 1.0f);
}

__device__ __forceinline__ v2f pk_fma(v2f a, v2f b, v2f c) {
    return __builtin_elementwise_fma(a, b, c);
}

template<int CTRL>
__device__ __forceinline__ float dppf(float v) {
    return __builtin_bit_cast(float, __builtin_amdgcn_update_dpp(
        0, __builtin_bit_cast(int, v), CTRL, 0xF, 0xF, true));
}
// reduce both v2f components across 8 consecutive lanes (bits [2:0])
__device__ __forceinline__ v2f red8v(v2f v) {
    v2f t;
    t.x = dppf<0xB1>(v.x);  t.y = dppf<0xB1>(v.y);  v = v + t;  // xor 1
    t.x = dppf<0x4E>(v.x);  t.y = dppf<0x4E>(v.y);  v = v + t;  // xor 2
    t.x = dppf<0x141>(v.x); t.y = dppf<0x141>(v.y); v = v + t;  // xor 4 (RHM)
    return v;
}

__global__ __launch_bounds__(768, 3)
void lstm3_g8(const float* __restrict__ x,
              const float* __restrict__ W0, const float* __restrict__ U0,
              const float* __restrict__ b0,
              const float* __restrict__ W1, const float* __restrict__ U1,
              const float* __restrict__ b1,
              const float* __restrict__ Wf, const float* __restrict__ bfv,
              const float* __restrict__ Wo, const float* __restrict__ bov,
              float* __restrict__ out)
{
    const int b   = blockIdx.x;
    const int tid = threadIdx.x;   // 0..767
    const int grp = tid >> 8;      // pipeline stage 0,1,2 (layer)
    const int lt  = tid & 255;     // 0..255 within group
    const int cg  = lt >> 3;       // col-group 0..31 (2 units x 4 gates)
    const int kg  = lt & 7;        // k-group 0..7 (16 k each; 0-3 in, 4-7 rec)
    const int up  = kg & 1;        // unit parity this lane activates
    const int myu = 2 * cg + up;   // my unit

    // LDS: lh[g][p] at (2g+p)*BUF ; lx[p] at (6+p)*BUF ; chunked [4][CH]
    __shared__ __align__(16) float ls[8 * BUF];
    __shared__ float lact[UNITS];
    float* const lsb = ls;

    // ---- weights: 8 cols x 16 k as v2f wt[16][4] (col pair = unit even/odd) --
    const float* Wsel = (grp == 0) ? W0 : W1;
    const float* Usel = (grp == 0) ? U0 : U1;
    const float* bsel = (grp == 0) ? b0 : b1;
    const float* Msel = (kg < 4) ? Wsel : Usel;

    v2f wt[16][4];
    float biasv[4];
#pragma unroll
    for (int g = 0; g < 4; ++g) {
        const int colb = (g << 6) + 2 * cg;
#pragma unroll
        for (int k = 0; k < 16; ++k) {
            const int r = (kg & 3) * 16 + k;
            wt[k][g] = (v2f){Msel[r * NCOL + colb], Msel[r * NCOL + colb + 1]};
        }
        biasv[g] = bsel[(g << 6) + myu];
    }

    // zero h buffers (both parities, all 3 layers)
    if (tid < 6 * BUF) lsb[tid] = 0.f;

    // preload x(0) into lx[1] (chunked)
    const float* xbase = x + (size_t)b * SEQT * FEAT;
    const bool xload = (grp == 0) && (lt < 16);
    float* xwp0 = lsb + 6 * BUF + CH * (lt >> 2) + 4 * (lt & 3);
    float* xwp1 = xwp0 + BUF;
    if (xload) *(float4*)xwp1 = *(const float4*)(xbase + lt * 4);
    __syncthreads();

    // per-lane operand chunk pointers, both parities
    // in: G0 <- lx, G1 <- lh0, G2 <- lh1 ; rec: lh[grp]
    const float* inB0 = (grp == 0) ? (lsb + 6 * BUF) : (lsb + (2 * (grp - 1) + 0) * BUF);
    const float* inB1 = inB0 + BUF;
    const float* rcB0 = lsb + (2 * grp + 0) * BUF;
    const float* rcB1 = rcB0 + BUF;
    const int chOff = (kg & 3) * CH;
    const float* opP0 = ((kg < 4) ? inB0 : rcB0) + chOff;
    const float* opP1 = ((kg < 4) ? inB1 : rcB1) + chOff;

    // h write pointers (lanes kg<2 write unit myu)
    float* hwp0 = lsb + (2 * grp + 0) * BUF + CH * (myu >> 4) + (myu & 15);
    float* hwp1 = hwp0 + BUF;

    float c = 0.f;

    for (int tk = 0; tk < SEQT + 2; ++tk) {
        const int p = tk & 1;          // write parity; reads use p^1
        const int t = tk - grp;
        const bool active = (t >= 0) && (t < SEQT);

        float4 xg;
        const bool loading = xload && (tk + 1 < SEQT);
        if (loading)
            xg = *(const float4*)(xbase + (size_t)(tk + 1) * FEAT + lt * 4);

        if (active) {
            const float* op = p ? opP0 : opP1;   // parity p^1 buffer
            float4 o0 = *(const float4*)(op);
            float4 o1 = *(const float4*)(op + 4);
            float4 o2 = *(const float4*)(op + 8);
            float4 o3 = *(const float4*)(op + 12);

            v2f acc[4];
#pragma unroll
            for (int g = 0; g < 4; ++g) acc[g] = (v2f){0.f, 0.f};

#define MAC(V, K)                                                     \
            {                                                         \
                v2f s = (v2f){(V), (V)};                              \
                acc[0] = pk_fma(s, wt[K][0], acc[0]);                 \
                acc[1] = pk_fma(s, wt[K][1], acc[1]);                 \
                acc[2] = pk_fma(s, wt[K][2], acc[2]);                 \
                acc[3] = pk_fma(s, wt[K][3], acc[3]);                 \
            }
            MAC(o0.x, 0)  MAC(o0.y, 1)  MAC(o0.z, 2)  MAC(o0.w, 3)
            MAC(o1.x, 4)  MAC(o1.y, 5)  MAC(o1.z, 6)  MAC(o1.w, 7)
            MAC(o2.x, 8)  MAC(o2.y, 9)  MAC(o2.z, 10) MAC(o2.w, 11)
            MAC(o3.x, 12) MAC(o3.y, 13) MAC(o3.z, 14) MAC(o3.w, 15)
#undef MAC

            v2f z0 = red8v(acc[0]);
            v2f z1 = red8v(acc[1]);
            v2f z2 = red8v(acc[2]);
            v2f z3 = red8v(acc[3]);

            const float zi = (up ? z0.y : z0.x) + biasv[0];
            const float zf = (up ? z1.y : z1.x) + biasv[1];
            const float zg = (up ? z2.y : z2.x) + biasv[2];
            const float zo = (up ? z3.y : z3.x) + biasv[3];

            const float ig = sig_(zi), fg = sig_(zf);
            const float gg = tanh_(zg), og = sig_(zo);
            c = fg * c + ig * gg;
            const float hn = og * tanh_(c);
            if (kg < 2) *(p ? hwp1 : hwp0) = hn;
        }

        if (loading)
            *(float4*)(p ? xwp1 : xwp0) = xg;

        __syncthreads();
    }

    // ---- dense head on final h2 (lh[2][1], chunked) ----
    const float* h2f = lsb + (2 * 2 + 1) * BUF;
    if (tid < UNITS) {
        float a = bfv[tid];
#pragma unroll
        for (int k = 0; k < UNITS; ++k)
            a += h2f[CH * (k >> 4) + (k & 15)] * Wf[k * 64 + tid];
        lact[tid] = fmaxf(a, 0.f);
    }
    __syncthreads();
    if (tid < OUTD) {
        float a = bov[tid];
#pragma unroll
        for (int k = 0; k < UNITS; ++k) a += lact[k] * Wo[k * OUTD + tid];
        out[b * OUTD + tid] = a;
    }
}

extern "C" void kernel_launch(void* const* d_in, const int* in_sizes, int n_in,
                              void* d_out, int out_size, void* d_ws, size_t ws_size,
                              hipStream_t stream) {
    const float* x   = (const float*)d_in[0];
    const float* W0  = (const float*)d_in[1];
    const float* U0  = (const float*)d_in[2];
    const float* b0  = (const float*)d_in[3];
    const float* W1  = (const float*)d_in[4];
    const float* U1  = (const float*)d_in[5];
    const float* b1  = (const float*)d_in[6];
    const float* Wf  = (const float*)d_in[7];
    const float* bfv = (const float*)d_in[8];
    const float* Wo  = (const float*)d_in[9];
    const float* bov = (const float*)d_in[10];
    float* out = (float*)d_out;

    lstm3_g8<<<BATCHN, 768, 0, stream>>>(x, W0, U0, b0, W1, U1, b1,
                                         Wf, bfv, Wo, bov, out);
}